// Round 1
// baseline (13214.653 us; speedup 1.0000x reference)
//
#include <hip/hip_runtime.h>

// LSTM: B=256, T=512, D=64, H=512, 2 layers + FC(last timestep).
// Strategy: persistent kernel, 8 batch-groups x 32 gate-slice WGs (=256 WGs,
// 1/CU). Weights held in VGPRs as fp16 MFMA B-fragments (256 VGPR/lane).
// Per timestep: fp16 MFMA gates GEMM (fp32 acc), LDS K-reduction, cell update,
// fp16 h exchange via global + per-group release/acquire barrier (agent scope).

#define BATCH 256
#define SEQ   512
#define DIN   64
#define HID   512

typedef _Float16 f16_t;
typedef __attribute__((ext_vector_type(8))) _Float16 f16x8;
typedef __attribute__((ext_vector_type(4))) float    f32x4;

__device__ inline f16x8 cvt8(const float* __restrict__ p) {
    f16x8 r;
#pragma unroll
    for (int j = 0; j < 8; j++) r[j] = (_Float16)p[j];
    return r;
}

__device__ inline float sgm(float v) { return 1.f / (1.f + __expf(-v)); }
__device__ inline float th(float v)  { return 1.f - 2.f / (__expf(2.f * v) + 1.f); }

// 256 threads = 4 waves. wave = (m, kh): m = M-half (16 batch rows), kh = K-half.
// Each WG (slice s of 32) owns h-dims [s*16, s*16+16) i.e. gate rows
// {nt*512 + s*16 + col} for nt in {i,f,g,o}.
__global__ __launch_bounds__(256, 1) void lstm_scan(
    const float* __restrict__ x,
    const float* __restrict__ wih0, const float* __restrict__ whh0,
    const float* __restrict__ bih0, const float* __restrict__ bhh0,
    const float* __restrict__ wih1, const float* __restrict__ whh1,
    const float* __restrict__ bih1, const float* __restrict__ bhh1,
    unsigned* __restrict__ cnt, f16_t* __restrict__ h1buf, f16_t* __restrict__ h0buf)
{
    __shared__ f32x4 red[2][4][64];  // K-half partial C exchange (8 KB)

    const int tid  = threadIdx.x;
    const int wave = tid >> 6, lane = tid & 63;
    const int m    = wave & 1, kh = wave >> 1;
    const int quad = lane >> 4, col = lane & 15;
    const int grp  = blockIdx.x & 7;    // batch group (XCD-local if round-robin)
    const int s    = blockIdx.x >> 3;   // gate-slice index 0..31
    unsigned* bar  = cnt + grp * 32;    // 128B-spaced per-group counter
    const int brow = grp * 32 + m * 16 + col;  // A-row (batch) this lane loads
    const int hd   = s * 16 + col;             // h-dim of this lane's N-column
    unsigned target = 0;

    f16x8 Wb[64];                       // weight B-frags, resident in VGPRs
    f32x4 cst = {0.f, 0.f, 0.f, 0.f};   // cell state (kh==0 waves only)
    float bias[4] = {0.f, 0.f, 0.f, 0.f};

    // ================= Layer 0: K = 576 = [h(512) | x(64)], 18 K-blocks ======
#pragma unroll
    for (int i = 0; i < 9; i++) {
        const int kb = kh * 9 + i;
        const int k0 = kb * 32 + quad * 8;
#pragma unroll
        for (int nt = 0; nt < 4; nt++) {
            const int gr = nt * HID + s * 16 + col;
            const float* src = (k0 < HID) ? (whh0 + (size_t)gr * HID + k0)
                                          : (wih0 + (size_t)gr * DIN + (k0 - HID));
            Wb[i * 4 + nt] = cvt8(src);
        }
    }
    if (kh == 0) {
#pragma unroll
        for (int nt = 0; nt < 4; nt++) {
            const int gr = nt * HID + s * 16 + col;
            bias[nt] = bih0[gr] + bhh0[gr];
        }
    }

    for (int t = 0; t < SEQ; t++) {
        f32x4 acc[4];
#pragma unroll
        for (int nt = 0; nt < 4; nt++) acc[nt] = (f32x4){0.f, 0.f, 0.f, 0.f};

#pragma unroll
        for (int i = 0; i < 9; i++) {
            const int kb = kh * 9 + i;
            if (kb < 16) {               // h_{t-1} part
                if (t > 0) {
                    const f16_t* ap = h0buf + ((size_t)brow * SEQ + (t - 1)) * HID
                                      + kb * 32 + quad * 8;
                    f16x8 a = *(const f16x8*)ap;
#pragma unroll
                    for (int nt = 0; nt < 4; nt++)
                        acc[nt] = __builtin_amdgcn_mfma_f32_16x16x32_f16(a, Wb[i * 4 + nt], acc[nt], 0, 0, 0);
                }
            } else {                     // x_t part (fp32 -> fp16)
                const float* px = x + ((size_t)brow * SEQ + t) * DIN + (kb * 32 - HID) + quad * 8;
                f16x8 a = cvt8(px);
#pragma unroll
                for (int nt = 0; nt < 4; nt++)
                    acc[nt] = __builtin_amdgcn_mfma_f32_16x16x32_f16(a, Wb[i * 4 + nt], acc[nt], 0, 0, 0);
            }
        }

        if (kh == 1) {
#pragma unroll
            for (int nt = 0; nt < 4; nt++) red[m][nt][lane] = acc[nt];
        }
        __syncthreads();
        if (kh == 0) {
#pragma unroll
            for (int nt = 0; nt < 4; nt++) {
                f32x4 p = red[m][nt][lane];
#pragma unroll
                for (int r = 0; r < 4; r++) acc[nt][r] += p[r];
            }
#pragma unroll
            for (int r = 0; r < 4; r++) {
                float gi = acc[0][r] + bias[0], gf = acc[1][r] + bias[1];
                float gg = acc[2][r] + bias[2], go = acc[3][r] + bias[3];
                float iv = sgm(gi), fv = sgm(gf), gv = th(gg), ov = sgm(go);
                float c = fv * cst[r] + iv * gv;
                cst[r] = c;
                float h = ov * th(c);
                const int b = grp * 32 + m * 16 + quad * 4 + r;
                h0buf[((size_t)b * SEQ + t) * HID + hd] = (f16_t)h;
            }
        }
        __syncthreads();                 // drain h stores (vmcnt 0 at barrier)
        target += 32;
        if (tid == 0) {
            __hip_atomic_fetch_add(bar, 1u, __ATOMIC_RELEASE, __HIP_MEMORY_SCOPE_AGENT);
            while (__hip_atomic_load(bar, __ATOMIC_RELAXED, __HIP_MEMORY_SCOPE_AGENT) < target)
                __builtin_amdgcn_s_sleep(1);
            (void)__hip_atomic_load(bar, __ATOMIC_ACQUIRE, __HIP_MEMORY_SCOPE_AGENT);
        }
        __syncthreads();
    }

    // ================= Layer 1: K = 1024 = [h0_t(512) | h1_{t-1}(512)] ======
#pragma unroll
    for (int i = 0; i < 16; i++) {
        const int kb = kh * 16 + i;
        const int k0 = kb * 32 + quad * 8;
#pragma unroll
        for (int nt = 0; nt < 4; nt++) {
            const int gr = nt * HID + s * 16 + col;
            const float* src = (k0 < HID) ? (wih1 + (size_t)gr * HID + k0)
                                          : (whh1 + (size_t)gr * HID + (k0 - HID));
            Wb[i * 4 + nt] = cvt8(src);
        }
    }
    if (kh == 0) {
#pragma unroll
        for (int nt = 0; nt < 4; nt++) {
            const int gr = nt * HID + s * 16 + col;
            bias[nt] = bih1[gr] + bhh1[gr];
        }
#pragma unroll
        for (int r = 0; r < 4; r++) cst[r] = 0.f;
    }

    for (int t = 0; t < SEQ; t++) {
        f32x4 acc[4];
#pragma unroll
        for (int nt = 0; nt < 4; nt++) acc[nt] = (f32x4){0.f, 0.f, 0.f, 0.f};

#pragma unroll
        for (int i = 0; i < 16; i++) {
            const int kb = kh * 16 + i;
            if (kb < 16) {               // h0_t part (always available)
                const f16_t* ap = h0buf + ((size_t)brow * SEQ + t) * HID + kb * 32 + quad * 8;
                f16x8 a = *(const f16x8*)ap;
#pragma unroll
                for (int nt = 0; nt < 4; nt++)
                    acc[nt] = __builtin_amdgcn_mfma_f32_16x16x32_f16(a, Wb[i * 4 + nt], acc[nt], 0, 0, 0);
            } else if (t > 0) {          // h1_{t-1} part
                const f16_t* ap = h1buf + ((size_t)(((t - 1) & 1) * BATCH + brow)) * HID
                                  + (kb * 32 - HID) + quad * 8;
                f16x8 a = *(const f16x8*)ap;
#pragma unroll
                for (int nt = 0; nt < 4; nt++)
                    acc[nt] = __builtin_amdgcn_mfma_f32_16x16x32_f16(a, Wb[i * 4 + nt], acc[nt], 0, 0, 0);
            }
        }

        if (kh == 1) {
#pragma unroll
            for (int nt = 0; nt < 4; nt++) red[m][nt][lane] = acc[nt];
        }
        __syncthreads();
        if (kh == 0) {
#pragma unroll
            for (int nt = 0; nt < 4; nt++) {
                f32x4 p = red[m][nt][lane];
#pragma unroll
                for (int r = 0; r < 4; r++) acc[nt][r] += p[r];
            }
#pragma unroll
            for (int r = 0; r < 4; r++) {
                float gi = acc[0][r] + bias[0], gf = acc[1][r] + bias[1];
                float gg = acc[2][r] + bias[2], go = acc[3][r] + bias[3];
                float iv = sgm(gi), fv = sgm(gf), gv = th(gg), ov = sgm(go);
                float c = fv * cst[r] + iv * gv;
                cst[r] = c;
                float h = ov * th(c);
                const int b = grp * 32 + m * 16 + quad * 4 + r;
                h1buf[((size_t)((t & 1) * BATCH + b)) * HID + hd] = (f16_t)h;
            }
        }
        __syncthreads();
        target += 32;
        if (tid == 0) {
            __hip_atomic_fetch_add(bar, 1u, __ATOMIC_RELEASE, __HIP_MEMORY_SCOPE_AGENT);
            while (__hip_atomic_load(bar, __ATOMIC_RELAXED, __HIP_MEMORY_SCOPE_AGENT) < target)
                __builtin_amdgcn_s_sleep(1);
            (void)__hip_atomic_load(bar, __ATOMIC_ACQUIRE, __HIP_MEMORY_SCOPE_AGENT);
        }
        __syncthreads();
    }
}

// out[b] = dot(h1_last[b], fc_w) + fc_b ; h1_last lives in ping-pong slot 1 (t=511).
__global__ void fc_k(const f16_t* __restrict__ h1buf, const float* __restrict__ fcw,
                     const float* __restrict__ fcb, float* __restrict__ out)
{
    const int b = blockIdx.x, lane = threadIdx.x;
    const f16_t* hp = h1buf + ((size_t)(BATCH + b)) * HID;  // slot 1
    float sum = 0.f;
#pragma unroll
    for (int j = 0; j < 8; j++) {
        const int k = lane * 8 + j;
        sum += (float)hp[k] * fcw[k];
    }
#pragma unroll
    for (int off = 32; off; off >>= 1) sum += __shfl_down(sum, off);
    if (lane == 0) out[b] = sum + fcb[0];
}

extern "C" void kernel_launch(void* const* d_in, const int* in_sizes, int n_in,
                              void* d_out, int out_size, void* d_ws, size_t ws_size,
                              hipStream_t stream)
{
    const float* x    = (const float*)d_in[0];
    const float* wih0 = (const float*)d_in[1];
    const float* whh0 = (const float*)d_in[2];
    const float* bih0 = (const float*)d_in[3];
    const float* bhh0 = (const float*)d_in[4];
    const float* wih1 = (const float*)d_in[5];
    const float* whh1 = (const float*)d_in[6];
    const float* bih1 = (const float*)d_in[7];
    const float* bhh1 = (const float*)d_in[8];
    const float* fcw  = (const float*)d_in[9];
    const float* fcb  = (const float*)d_in[10];
    float* out = (float*)d_out;

    unsigned char* ws = (unsigned char*)d_ws;
    unsigned* cnt = (unsigned*)ws;                                   // 4 KB
    f16_t* h1buf  = (f16_t*)(ws + 4096);                             // 2*256*512*2 = 512 KB
    f16_t* h0buf  = (f16_t*)(ws + 4096 + 2 * BATCH * HID * sizeof(f16_t)); // 128 MB

    hipMemsetAsync(ws, 0, 4096, stream);  // zero barrier counters (ws is 0xAA-poisoned)
    lstm_scan<<<dim3(256), dim3(256), 0, stream>>>(x, wih0, whh0, bih0, bhh0,
                                                   wih1, whh1, bih1, bhh1,
                                                   cnt, h1buf, h0buf);
    fc_k<<<dim3(BATCH), dim3(64), 0, stream>>>(h1buf, fcw, fcb, out);
}

// Round 2
// 8580.857 us; speedup vs baseline: 1.5400x; 1.5400x over previous
//
#include <hip/hip_runtime.h>

// 2-layer LSTM (B=256,T=512,D=64,H=512) + FC(last step), MI355X.
// Round 2: layer-pipelined persistent kernel.
//   256 blocks x 512 threads (1/CU). Waves 0-3: layer0 slice, waves 4-7: layer1
//   slice (same batch group g, same 16 h-dims s). L1 trails L0 by one iteration:
//   iteration it computes L0 step t=it and L1 step t=it-1. 513 rounds total.
// Cross-block exchange: h0/h1/flags via RELAXED agent-scope atomics (sc0 sc1,
//   IF$-coherent) -- NO acquire/release fences, so L2 keeps x/weights cached.
//   Producer flags (epoch counters) instead of atomic-RMW barrier; ordering by
//   the vmcnt(0) drain __syncthreads emits before s_barrier, then relaxed flag.

#define BATCH 256
#define SEQ   512
#define DIN   64
#define HID   512

typedef _Float16 f16_t;
typedef __attribute__((ext_vector_type(8))) _Float16 f16x8;
typedef __attribute__((ext_vector_type(4))) float    f32x4;

#define SCOPE_AGT __HIP_MEMORY_SCOPE_AGENT

__device__ inline f16x8 cvt8(const float* __restrict__ p) {
    f16x8 r;
#pragma unroll
    for (int j = 0; j < 8; j++) r[j] = (_Float16)p[j];
    return r;
}

// 16B coherence-point load as 2x u64 relaxed agent atomics (global_load_dwordx2 sc0 sc1).
__device__ inline f16x8 ldx8(const f16_t* p) {
    const unsigned long long* q = (const unsigned long long*)p;
    unsigned long long a = __hip_atomic_load(q,     __ATOMIC_RELAXED, SCOPE_AGT);
    unsigned long long b = __hip_atomic_load(q + 1, __ATOMIC_RELAXED, SCOPE_AGT);
    union { unsigned long long u[2]; f16x8 v; } c;
    c.u[0] = a; c.u[1] = b;
    return c.v;
}

// Pack (h[lane], h[lane+1]) into a dword; even-col lanes store coherently.
__device__ inline void st_h_pair(f16_t* base_even, int lane, float h) {
    float hn = __shfl_down(h, 1);
    if ((lane & 1) == 0) {
        union { struct { _Float16 lo, hi; } s; unsigned u; } pk;
        pk.s.lo = (_Float16)h; pk.s.hi = (_Float16)hn;
        __hip_atomic_store((unsigned*)base_even, pk.u, __ATOMIC_RELAXED, SCOPE_AGT);
    }
}

__device__ inline void poll1(unsigned* f, unsigned need, int lane) {
    unsigned* p = f + (lane & 31);
    for (;;) {
        unsigned v = __hip_atomic_load(p, __ATOMIC_RELAXED, SCOPE_AGT);
        if (__all((int)(v >= need))) break;
        __builtin_amdgcn_s_sleep(2);
    }
}

__device__ inline void poll2(unsigned* f0, unsigned n0, unsigned* f1, unsigned n1, int lane) {
    unsigned* p0 = f0 + (lane & 31);
    unsigned* p1 = f1 + (lane & 31);
    for (;;) {
        unsigned a = __hip_atomic_load(p0, __ATOMIC_RELAXED, SCOPE_AGT);
        unsigned b = __hip_atomic_load(p1, __ATOMIC_RELAXED, SCOPE_AGT);
        if (__all((int)((a >= n0) & (b >= n1)))) break;
        __builtin_amdgcn_s_sleep(2);
    }
}

__device__ inline float sgm(float v) { return 1.f / (1.f + __expf(-v)); }
__device__ inline float th(float v)  { return 1.f - 2.f / (__expf(2.f * v) + 1.f); }

__global__ __launch_bounds__(512, 2) void lstm_pipe(
    const float* __restrict__ x,
    const float* __restrict__ wih0, const float* __restrict__ whh0,
    const float* __restrict__ bih0, const float* __restrict__ bhh0,
    const float* __restrict__ wih1, const float* __restrict__ whh1,
    const float* __restrict__ bih1, const float* __restrict__ bhh1,
    unsigned* __restrict__ flags0, unsigned* __restrict__ flags1,
    f16_t* __restrict__ h1buf, f16_t* __restrict__ h0buf)
{
    __shared__ f32x4 red0[2][4][64];     // L0 partials: [m][nt][lane]   (8 KB)
    __shared__ f32x4 red1[3][8][64];     // L1 partials: [src-1][mt*4+nt][lane] (24 KB)

    const int tid  = threadIdx.x;
    const int half = tid >> 8;           // 0 = layer0, 1 = layer1
    const int wv   = (tid >> 6) & 3;     // wave within half
    const int lane = tid & 63;
    const int quad = lane >> 4, col = lane & 15;
    const int g    = blockIdx.x & 7;     // batch group (round-robin -> XCD-local, perf only)
    const int s    = blockIdx.x >> 3;    // h-dim slice (16 dims)

    unsigned* f0 = flags0 + g * 32;
    unsigned* f1 = flags1 + g * 32;

    f16x8 Wb[36];                        // weight B-frags (L0 uses 36, L1 uses 32)
    float cst[8]  = {0, 0, 0, 0, 0, 0, 0, 0};
    float bias[4] = {0, 0, 0, 0};

    // ---------------- weight / bias preload ----------------
    if (half == 0) {
        const int kh = wv >> 1;
#pragma unroll
        for (int i = 0; i < 9; i++) {
            const int kb = kh * 9 + i;
            const int k0 = kb * 32 + quad * 8;
#pragma unroll
            for (int nt = 0; nt < 4; nt++) {
                const int gr = nt * HID + s * 16 + col;
                const float* src = (k0 < HID) ? (whh0 + (size_t)gr * HID + k0)
                                              : (wih0 + (size_t)gr * DIN + (k0 - HID));
                Wb[i * 4 + nt] = cvt8(src);
            }
        }
        if (kh == 0) {
#pragma unroll
            for (int nt = 0; nt < 4; nt++) {
                const int gr = nt * HID + s * 16 + col;
                bias[nt] = bih0[gr] + bhh0[gr];
            }
        }
    } else {
#pragma unroll
        for (int i = 0; i < 8; i++) {
            const int kb = wv * 8 + i;
            const int k0 = kb * 32 + quad * 8;
#pragma unroll
            for (int nt = 0; nt < 4; nt++) {
                const int gr = nt * HID + s * 16 + col;
                const float* src = (kb < 16) ? (wih1 + (size_t)gr * HID + k0)
                                             : (whh1 + (size_t)gr * HID + (k0 - HID));
                Wb[i * 4 + nt] = cvt8(src);
            }
        }
        if (wv == 0) {
#pragma unroll
            for (int nt = 0; nt < 4; nt++) {
                const int gr = nt * HID + s * 16 + col;
                bias[nt] = bih1[gr] + bhh1[gr];
            }
        }
    }

    // ---------------- pipelined scan: iteration it = L0 step it, L1 step it-1 ----
    for (int it = 0; it <= SEQ; ++it) {
        // ---- phase A: flag polls (wave 0 of each half)
        if (half == 0) {
            if (wv == 0 && it >= 1 && it < SEQ) poll1(f0, (unsigned)it, lane);
        } else {
            if (wv == 0 && it >= 1) poll2(f0, (unsigned)it, f1, (unsigned)(it - 1), lane);
        }
        __syncthreads();

        f32x4 acc[8];
#pragma unroll
        for (int i = 0; i < 8; i++) acc[i] = (f32x4){0.f, 0.f, 0.f, 0.f};

        // ---- phase B: MFMA
        if (half == 0 && it < SEQ) {
            const int t  = it;
            const int m  = wv & 1, kh = wv >> 1;
            const int brow = g * 32 + m * 16 + col;
#pragma unroll
            for (int i = 0; i < 9; i++) {
                const int kb = kh * 9 + i;
                if (kb < 16) {
                    if (t > 0) {
                        f16x8 a = ldx8(h0buf + ((size_t)brow * SEQ + (t - 1)) * HID + kb * 32 + quad * 8);
#pragma unroll
                        for (int nt = 0; nt < 4; nt++)
                            acc[nt] = __builtin_amdgcn_mfma_f32_16x16x32_f16(a, Wb[i * 4 + nt], acc[nt], 0, 0, 0);
                    }
                } else {
                    f16x8 a = cvt8(x + ((size_t)brow * SEQ + t) * DIN + (kb * 32 - HID) + quad * 8);
#pragma unroll
                    for (int nt = 0; nt < 4; nt++)
                        acc[nt] = __builtin_amdgcn_mfma_f32_16x16x32_f16(a, Wb[i * 4 + nt], acc[nt], 0, 0, 0);
                }
            }
            if (kh == 1) {
#pragma unroll
                for (int nt = 0; nt < 4; nt++) red0[m][nt][lane] = acc[nt];
            }
        } else if (half == 1 && it >= 1) {
            const int t = it - 1;
#pragma unroll
            for (int i = 0; i < 8; i++) {
                const int kb = wv * 8 + i;
#pragma unroll
                for (int mt = 0; mt < 2; mt++) {
                    const int arow = g * 32 + mt * 16 + col;
                    if (kb < 16) {
                        f16x8 a = ldx8(h0buf + ((size_t)arow * SEQ + t) * HID + kb * 32 + quad * 8);
#pragma unroll
                        for (int nt = 0; nt < 4; nt++)
                            acc[mt * 4 + nt] = __builtin_amdgcn_mfma_f32_16x16x32_f16(a, Wb[i * 4 + nt], acc[mt * 4 + nt], 0, 0, 0);
                    } else if (t > 0) {
                        f16x8 a = ldx8(h1buf + ((size_t)(((t - 1) & 1) * BATCH + arow)) * HID + (kb - 16) * 32 + quad * 8);
#pragma unroll
                        for (int nt = 0; nt < 4; nt++)
                            acc[mt * 4 + nt] = __builtin_amdgcn_mfma_f32_16x16x32_f16(a, Wb[i * 4 + nt], acc[mt * 4 + nt], 0, 0, 0);
                    }
                }
            }
            if (wv > 0) {
#pragma unroll
                for (int j = 0; j < 8; j++) red1[wv - 1][j][lane] = acc[j];
            }
        }
        __syncthreads();

        // ---- phase C: reduce + cell update + coherent h store
        if (half == 0 && it < SEQ && (wv >> 1) == 0) {
            const int t = it, m = wv;
#pragma unroll
            for (int nt = 0; nt < 4; nt++) {
                f32x4 p = red0[m][nt][lane];
#pragma unroll
                for (int r = 0; r < 4; r++) acc[nt][r] += p[r];
            }
#pragma unroll
            for (int r = 0; r < 4; r++) {
                float gi = acc[0][r] + bias[0], gf = acc[1][r] + bias[1];
                float gg = acc[2][r] + bias[2], go = acc[3][r] + bias[3];
                float c = sgm(gf) * cst[r] + sgm(gi) * th(gg);
                cst[r] = c;
                float h = sgm(go) * th(c);
                const int b = g * 32 + m * 16 + quad * 4 + r;
                st_h_pair(h0buf + ((size_t)b * SEQ + t) * HID + s * 16 + col, lane, h);
            }
        } else if (half == 1 && it >= 1 && wv == 0) {
            const int t = it - 1;
#pragma unroll
            for (int src = 0; src < 3; src++) {
#pragma unroll
                for (int j = 0; j < 8; j++) {
                    f32x4 p = red1[src][j][lane];
#pragma unroll
                    for (int r = 0; r < 4; r++) acc[j][r] += p[r];
                }
            }
#pragma unroll
            for (int mt = 0; mt < 2; mt++) {
#pragma unroll
                for (int r = 0; r < 4; r++) {
                    float gi = acc[mt * 4 + 0][r] + bias[0], gf = acc[mt * 4 + 1][r] + bias[1];
                    float gg = acc[mt * 4 + 2][r] + bias[2], go = acc[mt * 4 + 3][r] + bias[3];
                    float c = sgm(gf) * cst[mt * 4 + r] + sgm(gi) * th(gg);
                    cst[mt * 4 + r] = c;
                    float h = sgm(go) * th(c);
                    const int b = g * 32 + mt * 16 + quad * 4 + r;
                    st_h_pair(h1buf + ((size_t)((t & 1) * BATCH + b)) * HID + s * 16 + col, lane, h);
                }
            }
        }
        __syncthreads();  // compiler emits s_waitcnt vmcnt(0) before s_barrier -> h stores drained

        // ---- phase D: publish epoch flags (relaxed; ordering via the barrier drain above)
        if (half == 0 && it < SEQ && tid == 0)
            __hip_atomic_store(&f0[s], (unsigned)(it + 1), __ATOMIC_RELAXED, SCOPE_AGT);
        if (half == 1 && it >= 1 && tid == 256)
            __hip_atomic_store(&f1[s], (unsigned)it, __ATOMIC_RELAXED, SCOPE_AGT);
    }
}

// out[b] = dot(h1[511][b], fc_w) + fc_b ; slot = 511&1 = 1. Launch-boundary
// acquire invalidates caches, so plain loads see the sc1-written data.
__global__ void fc_k(const f16_t* __restrict__ h1buf, const float* __restrict__ fcw,
                     const float* __restrict__ fcb, float* __restrict__ out)
{
    const int b = blockIdx.x, lane = threadIdx.x;
    const f16_t* hp = h1buf + ((size_t)(BATCH + b)) * HID;
    float sum = 0.f;
#pragma unroll
    for (int j = 0; j < 8; j++) {
        const int k = lane * 8 + j;
        sum += (float)hp[k] * fcw[k];
    }
#pragma unroll
    for (int off = 32; off; off >>= 1) sum += __shfl_down(sum, off);
    if (lane == 0) out[b] = sum + fcb[0];
}

extern "C" void kernel_launch(void* const* d_in, const int* in_sizes, int n_in,
                              void* d_out, int out_size, void* d_ws, size_t ws_size,
                              hipStream_t stream)
{
    const float* x    = (const float*)d_in[0];
    const float* wih0 = (const float*)d_in[1];
    const float* whh0 = (const float*)d_in[2];
    const float* bih0 = (const float*)d_in[3];
    const float* bhh0 = (const float*)d_in[4];
    const float* wih1 = (const float*)d_in[5];
    const float* whh1 = (const float*)d_in[6];
    const float* bih1 = (const float*)d_in[7];
    const float* bhh1 = (const float*)d_in[8];
    const float* fcw  = (const float*)d_in[9];
    const float* fcb  = (const float*)d_in[10];
    float* out = (float*)d_out;

    unsigned char* ws = (unsigned char*)d_ws;
    unsigned* flags0 = (unsigned*)ws;                 // 1 KB
    unsigned* flags1 = (unsigned*)(ws + 1024);        // 1 KB
    f16_t* h1buf = (f16_t*)(ws + 4096);               // 2*256*512*2 = 512 KB
    f16_t* h0buf = (f16_t*)(ws + 4096 + 2 * BATCH * HID * sizeof(f16_t));  // 128 MB

    hipMemsetAsync(ws, 0, 4096, stream);              // zero epoch flags
    lstm_pipe<<<dim3(256), dim3(512), 0, stream>>>(x, wih0, whh0, bih0, bhh0,
                                                   wih1, whh1, bih1, bhh1,
                                                   flags0, flags1, h1buf, h0buf);
    fc_k<<<dim3(BATCH), dim3(64), 0, stream>>>(h1buf, fcw, fcb, out);
}

// Round 3
// 8085.277 us; speedup vs baseline: 1.6344x; 1.0613x over previous
//
#include <hip/hip_runtime.h>

// 2-layer LSTM (B=256,T=512,D=64,H=512) + FC(last step), MI355X.
// Round 3: weights FORCED resident in registers (asm anti-remat pin),
// h0 ping-pong (IF$-resident), single-dword epoch counters, 2 barriers/round.
// 256 blocks x 512 threads (1/CU). Waves 0-3: layer0 (g,s), waves 4-7: layer1.
// Round it: L0 computes t=it, L1 computes t=it-1 (513 rounds).

#define BATCH 256
#define SEQ   512
#define DIN   64
#define HID   512

typedef _Float16 f16_t;
typedef __attribute__((ext_vector_type(8))) _Float16 f16x8;
typedef __attribute__((ext_vector_type(4))) float    f32x4;

#define SCOPE_AGT __HIP_MEMORY_SCOPE_AGENT

__device__ inline f16x8 cvt8(const float* __restrict__ p) {
    f16x8 r;
#pragma unroll
    for (int j = 0; j < 8; j++) r[j] = (_Float16)p[j];
    return r;
}

__device__ inline f16x8 cvt8v(f32x4 lo, f32x4 hi) {
    f16x8 r;
#pragma unroll
    for (int j = 0; j < 4; j++) { r[j] = (_Float16)lo[j]; r[4 + j] = (_Float16)hi[j]; }
    return r;
}

// 16B coherence-point load (2x u64 relaxed agent atomics -> IF$, bypass L1/L2).
__device__ inline f16x8 ldx8(const f16_t* p) {
    const unsigned long long* q = (const unsigned long long*)p;
    unsigned long long a = __hip_atomic_load(q,     __ATOMIC_RELAXED, SCOPE_AGT);
    unsigned long long b = __hip_atomic_load(q + 1, __ATOMIC_RELAXED, SCOPE_AGT);
    union { unsigned long long u[2]; f16x8 v; } c;
    c.u[0] = a; c.u[1] = b;
    return c.v;
}

// Pack (h[lane], h[lane+1]) into a dword; even-col lanes store coherently.
__device__ inline void st_h_pair(f16_t* base_even, int lane, float h) {
    float hn = __shfl_down(h, 1);
    if ((lane & 1) == 0) {
        union { struct { _Float16 lo, hi; } s; unsigned u; } pk;
        pk.s.lo = (_Float16)h; pk.s.hi = (_Float16)hn;
        __hip_atomic_store((unsigned*)base_even, pk.u, __ATOMIC_RELAXED, SCOPE_AGT);
    }
}

// All lanes load the SAME dword (1 transaction, broadcast). Monotone epoch.
__device__ inline void pollc(unsigned* p, unsigned need) {
    while (__hip_atomic_load(p, __ATOMIC_RELAXED, SCOPE_AGT) < need)
        __builtin_amdgcn_s_sleep(1);
}

__device__ inline float sgm(float v) { return 1.f / (1.f + __expf(-v)); }
__device__ inline float th(float v)  { return 1.f - 2.f / (__expf(2.f * v) + 1.f); }

__global__ __launch_bounds__(512, 2) void lstm_pipe(
    const float* __restrict__ x,
    const float* __restrict__ wih0, const float* __restrict__ whh0,
    const float* __restrict__ bih0, const float* __restrict__ bhh0,
    const float* __restrict__ wih1, const float* __restrict__ whh1,
    const float* __restrict__ bih1, const float* __restrict__ bhh1,
    unsigned* __restrict__ cnt, f16_t* __restrict__ h1buf, f16_t* __restrict__ h0buf)
{
    __shared__ f32x4 red0[2][4][64];     // L0 K-half partials           (8 KB)
    __shared__ f32x4 red1[3][8][64];     // L1 partials from waves 1..3  (24 KB)

    const int tid  = threadIdx.x;
    const int half = tid >> 8;           // 0 = layer0, 1 = layer1
    const int wv   = (tid >> 6) & 3;     // wave within half
    const int lane = tid & 63;
    const int quad = lane >> 4, col = lane & 15;
    const int g    = blockIdx.x & 7;     // batch group (XCD round-robin: perf only)
    const int s    = blockIdx.x >> 3;    // h-dim slice (16 dims)

    unsigned* c0 = cnt + g * 32;         // L0 epoch counter (one dword, own line)
    unsigned* c1 = cnt + 256 + g * 32;   // L1 epoch counter

    f16x8 Wb[36];                        // weight B-frags, pinned below
    float cst[8]  = {0, 0, 0, 0, 0, 0, 0, 0};
    float bias[4] = {0, 0, 0, 0};

    // ---------------- weight / bias preload (once) ----------------
    if (half == 0) {
        const int kh = wv >> 1;
#pragma unroll
        for (int i = 0; i < 9; i++) {
            const int kb = kh * 9 + i;
            const int k0 = kb * 32 + quad * 8;
#pragma unroll
            for (int nt = 0; nt < 4; nt++) {
                const int gr = nt * HID + s * 16 + col;
                const float* src = (k0 < HID) ? (whh0 + (size_t)gr * HID + k0)
                                              : (wih0 + (size_t)gr * DIN + (k0 - HID));
                Wb[i * 4 + nt] = cvt8(src);
            }
        }
#pragma unroll
        for (int i = 0; i < 36; i++) asm volatile("" : "+v"(Wb[i]));  // anti-remat pin
        if (kh == 0) {
#pragma unroll
            for (int nt = 0; nt < 4; nt++) {
                const int gr = nt * HID + s * 16 + col;
                bias[nt] = bih0[gr] + bhh0[gr];
            }
        }
    } else {
#pragma unroll
        for (int i = 0; i < 8; i++) {
            const int kb = wv * 8 + i;
            const int k0 = kb * 32 + quad * 8;
#pragma unroll
            for (int nt = 0; nt < 4; nt++) {
                const int gr = nt * HID + s * 16 + col;
                const float* src = (kb < 16) ? (wih1 + (size_t)gr * HID + k0)
                                             : (whh1 + (size_t)gr * HID + (k0 - HID));
                Wb[i * 4 + nt] = cvt8(src);
            }
        }
#pragma unroll
        for (int i = 0; i < 32; i++) asm volatile("" : "+v"(Wb[i]));  // anti-remat pin
        if (wv == 0) {
#pragma unroll
            for (int nt = 0; nt < 4; nt++) {
                const int gr = nt * HID + s * 16 + col;
                bias[nt] = bih1[gr] + bhh1[gr];
            }
        }
    }

    // ---------------- pipelined scan ----------------
    for (int it = 0; it <= SEQ; ++it) {
        // ---- phase A (no barrier): prefetch + per-wave poll
        f32x4 xr[4];
        if (half == 0 && (wv >> 1) == 1 && it < SEQ) {  // kh==1 waves own the x K-blocks
            const int brow = g * 32 + (wv & 1) * 16 + col;
            const float* px = x + ((size_t)brow * SEQ + it) * DIN + quad * 8;
            xr[0] = *(const f32x4*)px;        xr[1] = *(const f32x4*)(px + 4);
            xr[2] = *(const f32x4*)(px + 32); xr[3] = *(const f32x4*)(px + 36);
        }
        if (half == 0) {
            if (it >= 1 && it < SEQ) pollc(c0, 32u * it);
        } else if (it >= 1) {
            if (wv < 2) pollc(c0, 32u * it);            // h0[t] consumers
            else        pollc(c1, 32u * (it - 1));      // h1[t-1] consumers
        }

        f32x4 acc[8];
#pragma unroll
        for (int i = 0; i < 8; i++) acc[i] = (f32x4){0.f, 0.f, 0.f, 0.f};

        // ---- phase B: MFMA
        if (half == 0 && it < SEQ) {
            const int t = it;
            const int m = wv & 1, kh = wv >> 1;
            const int brow = g * 32 + m * 16 + col;
#pragma unroll
            for (int i = 0; i < 9; i++) {
                const int kb = kh * 9 + i;
                if (kb < 16) {
                    if (t > 0) {
                        f16x8 a = ldx8(h0buf + ((size_t)(((t - 1) & 1) * BATCH + brow)) * HID + kb * 32 + quad * 8);
#pragma unroll
                        for (int nt = 0; nt < 4; nt++)
                            acc[nt] = __builtin_amdgcn_mfma_f32_16x16x32_f16(a, Wb[i * 4 + nt], acc[nt], 0, 0, 0);
                    }
                } else {
                    f16x8 a = cvt8v(xr[(kb - 16) * 2], xr[(kb - 16) * 2 + 1]);
#pragma unroll
                    for (int nt = 0; nt < 4; nt++)
                        acc[nt] = __builtin_amdgcn_mfma_f32_16x16x32_f16(a, Wb[i * 4 + nt], acc[nt], 0, 0, 0);
                }
            }
            if (kh == 1) {
#pragma unroll
                for (int nt = 0; nt < 4; nt++) red0[m][nt][lane] = acc[nt];
            }
        } else if (half == 1 && it >= 1) {
            const int t = it - 1;
#pragma unroll
            for (int i = 0; i < 8; i++) {
                const int kb = wv * 8 + i;
#pragma unroll
                for (int mt = 0; mt < 2; mt++) {
                    const int arow = g * 32 + mt * 16 + col;
                    if (kb < 16) {
                        f16x8 a = ldx8(h0buf + ((size_t)((t & 1) * BATCH + arow)) * HID + kb * 32 + quad * 8);
#pragma unroll
                        for (int nt = 0; nt < 4; nt++)
                            acc[mt * 4 + nt] = __builtin_amdgcn_mfma_f32_16x16x32_f16(a, Wb[i * 4 + nt], acc[mt * 4 + nt], 0, 0, 0);
                    } else if (t > 0) {
                        f16x8 a = ldx8(h1buf + ((size_t)(((t - 1) & 1) * BATCH + arow)) * HID + (kb - 16) * 32 + quad * 8);
#pragma unroll
                        for (int nt = 0; nt < 4; nt++)
                            acc[mt * 4 + nt] = __builtin_amdgcn_mfma_f32_16x16x32_f16(a, Wb[i * 4 + nt], acc[mt * 4 + nt], 0, 0, 0);
                    }
                }
            }
            if (wv > 0) {
#pragma unroll
                for (int j = 0; j < 8; j++) red1[wv - 1][j][lane] = acc[j];
            }
        }
        __syncthreads();                                 // bar1: red published

        // ---- phase C: reduce + cell update + coherent h store
        if (half == 0 && it < SEQ && (wv >> 1) == 0) {
            const int t = it, m = wv;
#pragma unroll
            for (int nt = 0; nt < 4; nt++) {
                f32x4 p = red0[m][nt][lane];
#pragma unroll
                for (int r = 0; r < 4; r++) acc[nt][r] += p[r];
            }
#pragma unroll
            for (int r = 0; r < 4; r++) {
                float gi = acc[0][r] + bias[0], gf = acc[1][r] + bias[1];
                float gg = acc[2][r] + bias[2], go = acc[3][r] + bias[3];
                float c = sgm(gf) * cst[r] + sgm(gi) * th(gg);
                cst[r] = c;
                float h = sgm(go) * th(c);
                const int b = g * 32 + m * 16 + quad * 4 + r;
                st_h_pair(h0buf + ((size_t)((t & 1) * BATCH + b)) * HID + s * 16 + col, lane, h);
            }
        } else if (half == 1 && it >= 1 && wv == 0) {
            const int t = it - 1;
#pragma unroll
            for (int src = 0; src < 3; src++) {
#pragma unroll
                for (int j = 0; j < 8; j++) {
                    f32x4 p = red1[src][j][lane];
#pragma unroll
                    for (int r = 0; r < 4; r++) acc[j][r] += p[r];
                }
            }
#pragma unroll
            for (int mt = 0; mt < 2; mt++) {
#pragma unroll
                for (int r = 0; r < 4; r++) {
                    float gi = acc[mt * 4 + 0][r] + bias[0], gf = acc[mt * 4 + 1][r] + bias[1];
                    float gg = acc[mt * 4 + 2][r] + bias[2], go = acc[mt * 4 + 3][r] + bias[3];
                    float c = sgm(gf) * cst[mt * 4 + r] + sgm(gi) * th(gg);
                    cst[mt * 4 + r] = c;
                    float h = sgm(go) * th(c);
                    const int b = g * 32 + mt * 16 + quad * 4 + r;
                    st_h_pair(h1buf + ((size_t)((t & 1) * BATCH + b)) * HID + s * 16 + col, lane, h);
                }
            }
        }
        __syncthreads();                                 // bar2: vmcnt(0) drain of h stores

        // ---- phase D: bump epoch counters (relaxed RMW at IF$; ordered after drain)
        if (half == 0 && it < SEQ && tid == 0)
            __hip_atomic_fetch_add(c0, 1u, __ATOMIC_RELAXED, SCOPE_AGT);
        if (half == 1 && it >= 1 && tid == 256)
            __hip_atomic_fetch_add(c1, 1u, __ATOMIC_RELAXED, SCOPE_AGT);
    }
}

// out[b] = dot(h1[511][b], fc_w) + fc_b ; slot = 511&1 = 1.
__global__ void fc_k(const f16_t* __restrict__ h1buf, const float* __restrict__ fcw,
                     const float* __restrict__ fcb, float* __restrict__ out)
{
    const int b = blockIdx.x, lane = threadIdx.x;
    const f16_t* hp = h1buf + ((size_t)(BATCH + b)) * HID;
    float sum = 0.f;
#pragma unroll
    for (int j = 0; j < 8; j++) {
        const int k = lane * 8 + j;
        sum += (float)hp[k] * fcw[k];
    }
#pragma unroll
    for (int off = 32; off; off >>= 1) sum += __shfl_down(sum, off);
    if (lane == 0) out[b] = sum + fcb[0];
}

extern "C" void kernel_launch(void* const* d_in, const int* in_sizes, int n_in,
                              void* d_out, int out_size, void* d_ws, size_t ws_size,
                              hipStream_t stream)
{
    const float* x    = (const float*)d_in[0];
    const float* wih0 = (const float*)d_in[1];
    const float* whh0 = (const float*)d_in[2];
    const float* bih0 = (const float*)d_in[3];
    const float* bhh0 = (const float*)d_in[4];
    const float* wih1 = (const float*)d_in[5];
    const float* whh1 = (const float*)d_in[6];
    const float* bih1 = (const float*)d_in[7];
    const float* bhh1 = (const float*)d_in[8];
    const float* fcw  = (const float*)d_in[9];
    const float* fcb  = (const float*)d_in[10];
    float* out = (float*)d_out;

    unsigned char* ws = (unsigned char*)d_ws;
    unsigned* cnt = (unsigned*)ws;                                   // 2 KB used
    f16_t* h1buf  = (f16_t*)(ws + 4096);                             // 512 KB (2 slots)
    f16_t* h0buf  = (f16_t*)(ws + 4096 + 2 * BATCH * HID * sizeof(f16_t)); // 512 KB (2 slots)

    hipMemsetAsync(ws, 0, 4096, stream);  // zero epoch counters
    lstm_pipe<<<dim3(256), dim3(512), 0, stream>>>(x, wih0, whh0, bih0, bhh0,
                                                   wih1, whh1, bih1, bhh1,
                                                   cnt, h1buf, h0buf);
    fc_k<<<dim3(BATCH), dim3(64), 0, stream>>>(h1buf, fcw, fcb, out);
}